// Round 16
// baseline (521.942 us; speedup 1.0000x reference)
//
#include <hip/hip_runtime.h>
#include <hip/hip_bf16.h>

// DigitCaps dynamic routing. Output fp32.
// R16: producer/tail fusion. R15 proved fused-build costs 32x redundancy;
// R13's amortized build is right but pays 11 dispatch slots (~99us). Here:
// 6 dispatches. D1 = sgemm(576 producers) + squash(320 tail blocks spinning
// on a relaxed agent-scope done-counter); D2 = AG(144) + RB-tail(180).
// Fence pattern == R11's gsync (bit-correct there); producers never wait.
// Co-residency: 896 blocks << ~2048 capacity -> no deadlock.
#define B 512
#define IC 1152
#define QD 8
#define OD 10
#define PD 16
#define KD (IC * QD)       // 9216
#define NKB (KD / 32)      // 288
#define NCS 72             // K-chunks in sgemm; 288/72 = 4 kb-steps
#define KSTEPS (NKB / NCS)
#define SUNITS 576
#define AUNITS 144
#define RBBLK 180
#define IO (IC * OD)       // 11520
#define SOP (B * OD * PD)  // 81920

typedef short bf16x8 __attribute__((ext_vector_type(8)));
typedef float f32x4 __attribute__((ext_vector_type(4)));

__device__ __forceinline__ short f2bf(float f) {
  union { float f; unsigned u; } x;
  x.f = f;
  unsigned r = x.u + 0x7FFFu + ((x.u >> 16) & 1u);  // RNE
  return (short)(r >> 16);
}

// ---- one-way completion counter (R11-proven fence pattern) -----------------
__device__ __forceinline__ void signal_done(int* cnt) {
  __syncthreads();  // compiler emits s_waitcnt vmcnt(0) before s_barrier
  if (threadIdx.x == 0) {
    __threadfence();
    __hip_atomic_fetch_add(cnt, 1, __ATOMIC_RELEASE, __HIP_MEMORY_SCOPE_AGENT);
  }
}
__device__ __forceinline__ void wait_done(int* cnt, int target) {
  if (threadIdx.x == 0) {
    while (__hip_atomic_load(cnt, __ATOMIC_RELAXED, __HIP_MEMORY_SCOPE_AGENT) < target)
      __builtin_amdgcn_s_sleep(8);
    __threadfence();
  }
  __syncthreads();
}

// ---- RB0: uniform Bs (iter0) + zero the 8 counter slots --------------------
// Bs[kb][n][quad][j] = bf16((1/IC) * W[i,o,p,q]); i=kb*4+quad, n=o*16+p.
__global__ __launch_bounds__(256) void rb0_kernel(const float* __restrict__ W,
                                                  short* __restrict__ Bs,
                                                  int* __restrict__ cnt) {
  if (blockIdx.x == 0 && threadIdx.x < 8) cnt[threadIdx.x] = 0;
  const int t = blockIdx.x * 256 + threadIdx.x;  // < 46080
  const int kb = t / 160, n = t % 160;
  const int o = n >> 4, p = n & 15;
  const float cu = 1.0f / (float)IC;
  short ov[32];
#pragma unroll
  for (int quad = 0; quad < 4; ++quad) {
    const int i = kb * 4 + quad;
    const float4* wp = (const float4*)(W + (((size_t)i * OD + o) * PD + p) * QD);
    const float4 w0 = wp[0], w1 = wp[1];
    ov[quad * 8 + 0] = f2bf(cu * w0.x); ov[quad * 8 + 1] = f2bf(cu * w0.y);
    ov[quad * 8 + 2] = f2bf(cu * w0.z); ov[quad * 8 + 3] = f2bf(cu * w0.w);
    ov[quad * 8 + 4] = f2bf(cu * w1.x); ov[quad * 8 + 5] = f2bf(cu * w1.y);
    ov[quad * 8 + 6] = f2bf(cu * w1.z); ov[quad * 8 + 7] = f2bf(cu * w1.w);
  }
  int4* dst = (int4*)(Bs + (size_t)t * 32);
  const int4* src = (const int4*)ov;
#pragma unroll
  for (int j = 0; j < 4; ++j) dst[j] = src[j];
}

// ---- D1: sgemm producers (R13-proven unit) + squash tail (R13-proven) ------
__global__ __launch_bounds__(256) void d1_kernel(const float* __restrict__ x,
                                                 const short* __restrict__ Bs,
                                                 float* __restrict__ s_part,
                                                 short* __restrict__ vB,
                                                 float* __restrict__ out,
                                                 int* __restrict__ cnt,
                                                 int write_out) {
  const int tid = threadIdx.x;
  if (blockIdx.x < SUNITS) {
    const int wave = tid >> 6, lane = tid & 63;
    const int ln = lane & 15, quad = lane >> 4;
    const int cz = blockIdx.x % NCS, mb = blockIdx.x / NCS;
    const int m0 = mb * 64 + wave * 16;
    f32x4 acc[10] = {};
    const float* arow = x + (size_t)(m0 + ln) * KD + quad * 8;
#pragma unroll
    for (int step = 0; step < KSTEPS; ++step) {
      const int kb = cz * KSTEPS + step;
      const float* ap = arow + (size_t)kb * 32;
      const f32x4 a0 = *(const f32x4*)ap;
      const f32x4 a1 = *(const f32x4*)(ap + 4);
      bf16x8 af;
      af[0] = f2bf(a0[0]); af[1] = f2bf(a0[1]); af[2] = f2bf(a0[2]); af[3] = f2bf(a0[3]);
      af[4] = f2bf(a1[0]); af[5] = f2bf(a1[1]); af[6] = f2bf(a1[2]); af[7] = f2bf(a1[3]);
      const short* bp = Bs + (size_t)kb * 5120 + ln * 32 + quad * 8;
#pragma unroll
      for (int nt = 0; nt < 10; ++nt) {
        const bf16x8 bf = *(const bf16x8*)(bp + nt * 512);
        acc[nt] = __builtin_amdgcn_mfma_f32_16x16x32_bf16(af, bf, acc[nt], 0, 0, 0);
      }
    }
    // C/D: row = quad*4+r (b), col = ln (p) [m89-verified]
    float* sp = s_part + (size_t)cz * SOP;
#pragma unroll
    for (int nt = 0; nt < 10; ++nt)
#pragma unroll
      for (int r = 0; r < 4; ++r)
        sp[(size_t)(m0 + quad * 4 + r) * 160 + nt * 16 + ln] = acc[nt][r];
    signal_done(cnt);
  } else {
    wait_done(cnt, SUNITS);
    const int t = (blockIdx.x - SUNITS) * 256 + tid;  // < 81920
    float sv = 0.f;
#pragma unroll 8
    for (int ch = 0; ch < NCS; ++ch) sv += s_part[(size_t)ch * SOP + t];
    float sq = sv * sv;
#pragma unroll
    for (int m = 1; m < 16; m <<= 1) sq += __shfl_xor(sq, m, 16);
    const float norm = sqrtf(sq + 1e-8f);
    const float val = sv * (sq / ((1.f + sq) * norm));
    if (write_out) {
      out[t] = val;
    } else {
      const int b = t / 160, n = t - b * 160;
      vB[((size_t)(b >> 5) * 160 + n) * 32 + (b & 31)] = f2bf(val);
    }
  }
}

// ---- D2: AG producers (R13/R14/R15-proven) + RB tail (R13-proven) ----------
// mode 1: bij = u_t (tail block 0 persists bijA); mode 2: bij = bijA + u_t.
__global__ __launch_bounds__(256) void d2_kernel(const float* __restrict__ x,
                                                 const float* __restrict__ W,
                                                 const short* __restrict__ vB,
                                                 float* __restrict__ u_t,
                                                 float* __restrict__ bijA,
                                                 short* __restrict__ Bs,
                                                 int* __restrict__ cnt,
                                                 int mode) {
  __shared__ __align__(16) char smem[48000];
  const int tid = threadIdx.x;
  if (blockIdx.x < AUNITS) {
    short* Abuf = (short*)smem;  // 16KB
    const int ig8 = blockIdx.x;
    const int mt = tid >> 6, lane = tid & 63;
    const int ln = lane & 15, quad = lane >> 4;
    f32x4 acc[10] = {};
    for (int kq = 0; kq < 4; ++kq) {
      const int b0 = kq * 128;
      __syncthreads();
#pragma unroll
      for (int j = 0; j < 8; ++j) {  // x -> A-frag layout [m120-verified]
        const int idx = tid + j * 256;
        const int b = idx >> 4, f4 = idx & 15;
        const float4 vx = *(const float4*)(x + (size_t)(b0 + b) * KD + ig8 * 64 + f4 * 4);
        const int kbl = b >> 5, qk = (b & 31) >> 3, jj = b & 7;
        const int mtt = f4 >> 2, mlb = (f4 & 3) * 4;
        short* dst = Abuf + (((mtt * 4 + kbl) * 64 + qk * 16 + mlb) * 8 + jj);
        dst[0] = f2bf(vx.x); dst[8] = f2bf(vx.y); dst[16] = f2bf(vx.z); dst[24] = f2bf(vx.w);
      }
      __syncthreads();
#pragma unroll
      for (int kbb = 0; kbb < 4; ++kbb) {
        const bf16x8 af = *(const bf16x8*)(Abuf + ((mt * 4 + kbb) * 64 + lane) * 8);
        const short* bp = vB + ((size_t)((kq * 4 + kbb) * 160) + ln) * 32 + quad * 8;
#pragma unroll
        for (int nt = 0; nt < 10; ++nt) {
          const bf16x8 bf = *(const bf16x8*)(bp + nt * 512);
          acc[nt] = __builtin_amdgcn_mfma_f32_16x16x32_bf16(af, bf, acc[nt], 0, 0, 0);
        }
      }
    }
    const int lane2 = tid & 63;
    const int ln2 = lane2 & 15, quad2 = lane2 >> 4;
    const int i = ig8 * 8 + (tid >> 6) * 2 + (quad2 >> 1);
    const int qb = (quad2 & 1) * 4;
#pragma unroll
    for (int nt = 0; nt < 10; ++nt) {
      const float4 wv = *(const float4*)(W + (((size_t)i * OD + nt) * PD + ln2) * QD + qb);
      float pa = acc[nt][0] * wv.x + acc[nt][1] * wv.y + acc[nt][2] * wv.z + acc[nt][3] * wv.w;
      pa += __shfl_xor(pa, 1); pa += __shfl_xor(pa, 2); pa += __shfl_xor(pa, 4);
      pa += __shfl_xor(pa, 8); pa += __shfl_xor(pa, 16);
      if ((lane2 & 31) == 0) u_t[(size_t)nt * IC + i] = pa * (1.0f / (float)B);
    }
    signal_done(cnt);
  } else {
    float* bl = (float*)smem;                  // IO floats = 46080 B
    __shared__ float wred[4][OD];
    __shared__ float mxS[OD], invS[OD];
    const int tb = blockIdx.x - AUNITS;        // 0..179
    const int wave = tid >> 6, lane = tid & 63;
    wait_done(cnt, AUNITS);
    // redundant per-block softmax over i for all o (R13 RB-proven form)
    float lmax[OD];
#pragma unroll
    for (int o = 0; o < OD; ++o) lmax[o] = -1e30f;
    for (int i = tid; i < IC; i += 256) {
#pragma unroll
      for (int o = 0; o < OD; ++o) {
        float t = u_t[o * IC + i];
        if (mode == 2) t += bijA[o * IC + i];
        if (mode == 1 && tb == 0) bijA[o * IC + i] = t;
        bl[i * OD + o] = t;
        lmax[o] = fmaxf(lmax[o], t);
      }
    }
#pragma unroll
    for (int o = 0; o < OD; ++o) {
      float m = lmax[o];
#pragma unroll
      for (int s = 1; s < 64; s <<= 1) m = fmaxf(m, __shfl_xor(m, s));
      if (lane == 0) wred[wave][o] = m;
    }
    __syncthreads();
    if (tid < OD)
      mxS[tid] = fmaxf(fmaxf(wred[0][tid], wred[1][tid]),
                       fmaxf(wred[2][tid], wred[3][tid]));
    __syncthreads();
    float lsum[OD];
#pragma unroll
    for (int o = 0; o < OD; ++o) lsum[o] = 0.f;
    for (int i = tid; i < IC; i += 256) {
#pragma unroll
      for (int o = 0; o < OD; ++o) {
        const float e = __expf(bl[i * OD + o] - mxS[o]);
        bl[i * OD + o] = e;
        lsum[o] += e;
      }
    }
    __syncthreads();
#pragma unroll
    for (int o = 0; o < OD; ++o) {
      float s = lsum[o];
#pragma unroll
      for (int st = 1; st < 64; st <<= 1) s += __shfl_xor(s, st);
      if (lane == 0) wred[wave][o] = s;
    }
    __syncthreads();
    if (tid < OD)
      invS[tid] = 1.f / (wred[0][tid] + wred[1][tid] + wred[2][tid] + wred[3][tid]);
    __syncthreads();
    // build one Bs item (kb,n) per thread (R13 RB-proven)
    const int t = tb * 256 + tid;  // < 46080
    const int kb = t / 160, n = t % 160;
    const int o = n >> 4, p = n & 15;
    short ov[32];
#pragma unroll
    for (int quad = 0; quad < 4; ++quad) {
      const int i = kb * 4 + quad;
      const float ci = bl[i * OD + o] * invS[o];
      const float4* wp = (const float4*)(W + (((size_t)i * OD + o) * PD + p) * QD);
      const float4 w0 = wp[0], w1 = wp[1];
      ov[quad * 8 + 0] = f2bf(ci * w0.x); ov[quad * 8 + 1] = f2bf(ci * w0.y);
      ov[quad * 8 + 2] = f2bf(ci * w0.z); ov[quad * 8 + 3] = f2bf(ci * w0.w);
      ov[quad * 8 + 4] = f2bf(ci * w1.x); ov[quad * 8 + 5] = f2bf(ci * w1.y);
      ov[quad * 8 + 6] = f2bf(ci * w1.z); ov[quad * 8 + 7] = f2bf(ci * w1.w);
    }
    int4* dst = (int4*)(Bs + (size_t)t * 32);
    const int4* src = (const int4*)ov;
#pragma unroll
    for (int j = 0; j < 4; ++j) dst[j] = src[j];
  }
}

// ---- launch: 6 dispatches ---------------------------------------------------

extern "C" void kernel_launch(void* const* d_in, const int* in_sizes, int n_in,
                              void* d_out, int out_size, void* d_ws, size_t ws_size,
                              hipStream_t stream) {
  const float* x = (const float*)d_in[0];  // [512,1152,8] fp32
  const float* W = (const float*)d_in[1];  // [1152,10,16,8] fp32
  float* out = (float*)d_out;              // [512,10,16] fp32

  // workspace ~27 MB of ~268 MB; counters zeroed by rb0 every call.
  float* ws = (float*)d_ws;
  float* s_part = ws;                        // 72*81920
  float* u_t = s_part + (size_t)NCS * SOP;   // 11520
  float* bijA = u_t + IO;                    // 11520
  short* vB = (short*)(bijA + IO);           // 16*160*32 shorts
  short* Bs = vB + (size_t)16 * 160 * 32;    // 288*160*32 shorts
  int* cnt = (int*)(Bs + (size_t)NKB * 160 * 32);  // 8 ints

  rb0_kernel<<<RBBLK, 256, 0, stream>>>(W, Bs, cnt);
  d1_kernel<<<SUNITS + 320, 256, 0, stream>>>(x, Bs, s_part, vB, out, cnt + 0, 0);
  d2_kernel<<<AUNITS + RBBLK, 256, 0, stream>>>(x, W, vB, u_t, bijA, Bs, cnt + 1, 1);
  d1_kernel<<<SUNITS + 320, 256, 0, stream>>>(x, Bs, s_part, vB, out, cnt + 2, 0);
  d2_kernel<<<AUNITS + RBBLK, 256, 0, stream>>>(x, W, vB, u_t, bijA, Bs, cnt + 3, 2);
  d1_kernel<<<SUNITS + 320, 256, 0, stream>>>(x, Bs, s_part, vB, out, cnt + 4, 1);
}

// Round 17
// 219.624 us; speedup vs baseline: 2.3765x; 2.3765x over previous
//
#include <hip/hip_runtime.h>
#include <hip/hip_bf16.h>

// DigitCaps dynamic routing. Output fp32.
// R17: 8 dispatches, NO intra-kernel cross-block sync (R9/R11/R16: any such
// sync costs ~90-185us on MI355X; kernel boundaries do the flush at ~9us).
// F restructured vs R15 (which was 40us/dispatch from 1:1 build:MFMA + serial
// chain): block=(o,cz) over all 512 b -> each wave builds its 4 B-frags ONCE
// in registers, reuses 8x across m-tiles (8 independent A-loads + 8 MFMAs on
// distinct accs per kb = MLP + MFMA ILP). blockIdx=o*72+cz: same-cz -> same
// XCD (stride 72 = 0 mod 8) so the 10x o-read of x stays in per-XCD L2.
// squash/agg are R13-verified forms verbatim. Chain: F,S,A, F,S,A, F,S.
#define B 512
#define IC 1152
#define QD 8
#define OD 10
#define PD 16
#define KD (IC * QD)       // 9216
#define NKB (KD / 32)      // 288
#define NCS 72             // K-chunks in F; 288/72 = 4 kb each
#define IO (IC * OD)       // 11520
#define SOP (B * OD * PD)  // 81920

typedef short bf16x8 __attribute__((ext_vector_type(8)));
typedef float f32x4 __attribute__((ext_vector_type(4)));

__device__ __forceinline__ short f2bf(float f) {
  union { float f; unsigned u; } x;
  x.f = f;
  unsigned r = x.u + 0x7FFFu + ((x.u >> 16) & 1u);  // RNE
  return (short)(r >> 16);
}
__device__ __forceinline__ unsigned pkbf(float a, float b) {
  union { __hip_bfloat162 h; unsigned u; } c;
  c.h = __float22bfloat162_rn(make_float2(a, b));  // v_cvt_pk_bf16_f32 (RNE)
  return c.u;
}

// ---- F: block = (o, cz). Per-o softmax (block-local, R15-proven), 4 B-frags
// built once in regs, m-loop over all 512 b-rows; s_part[cz][b][o*16+p].
// mode 0: c uniform. mode 1: bij = u_t (cz==0 persists bijA). mode 2: +bijA.
__global__ __launch_bounds__(256) void f_kernel(const float* __restrict__ x,
                                                const float* __restrict__ W,
                                                const float* __restrict__ u_t,
                                                float* __restrict__ bijA,
                                                float* __restrict__ s_part,
                                                int mode) {
  __shared__ float cS[IC];
  __shared__ float redA[4], redB[4];
  const int tid = threadIdx.x;
  const int o = blockIdx.x / NCS;   // blockIdx = o*72 + cz
  const int cz = blockIdx.x % NCS;
  const int wave = tid >> 6, lane = tid & 63;
  const int ln = lane & 15, quad = lane >> 4;

  float inv = 0.f;
  if (mode != 0) {
    float lm = -1e30f;
#pragma unroll
    for (int k = 0; k < 5; ++k) {
      const int i = tid + k * 256;
      if (i < IC) {
        float t = u_t[o * IC + i];
        if (mode == 2) t += bijA[o * IC + i];
        if (mode == 1 && cz == 0) bijA[o * IC + i] = t;
        cS[i] = t;
        lm = fmaxf(lm, t);
      }
    }
#pragma unroll
    for (int s = 1; s < 64; s <<= 1) lm = fmaxf(lm, __shfl_xor(lm, s));
    if (lane == 0) redA[wave] = lm;
    __syncthreads();
    const float mx = fmaxf(fmaxf(redA[0], redA[1]), fmaxf(redA[2], redA[3]));
    float ls = 0.f;
#pragma unroll
    for (int k = 0; k < 5; ++k) {
      const int i = tid + k * 256;
      if (i < IC) {
        const float e = __expf(cS[i] - mx);
        cS[i] = e;
        ls += e;
      }
    }
#pragma unroll
    for (int s = 1; s < 64; s <<= 1) ls += __shfl_xor(ls, s);
    if (lane == 0) redB[wave] = ls;
    __syncthreads();
    inv = 1.f / (redB[0] + redB[1] + redB[2] + redB[3]);
  }

  // build 4 B-frags once (lane (ln,quad): B[k=quad*8+j][n=ln], i=kb*4+quad, q=j)
  const float cu = 1.0f / (float)IC;
  uint4 bfr[4];
#pragma unroll
  for (int k4 = 0; k4 < 4; ++k4) {
    const int kb = cz * 4 + k4;
    const int i = kb * 4 + quad;
    const float ci = mode ? cS[i] * inv : cu;
    const float* wr = W + ((size_t)(i * OD + o) * PD + ln) * QD;  // W[i][o][p=ln][:]
    const f32x4 w0 = *(const f32x4*)wr;
    const f32x4 w1 = *(const f32x4*)(wr + 4);
    bfr[k4].x = pkbf(ci * w0[0], ci * w0[1]);
    bfr[k4].y = pkbf(ci * w0[2], ci * w0[3]);
    bfr[k4].z = pkbf(ci * w1[0], ci * w1[1]);
    bfr[k4].w = pkbf(ci * w1[2], ci * w1[3]);
  }

  // m-loop: wave covers m-tiles wave*8 .. wave*8+7 (16 rows each). Per kb:
  // 8 independent A-loads -> 8 MFMAs on distinct accumulators.
  f32x4 acc[8] = {};
#pragma unroll
  for (int k4 = 0; k4 < 4; ++k4) {
    const int kofs = (cz * 4 + k4) * 32 + quad * 8;
#pragma unroll
    for (int mt = 0; mt < 8; ++mt) {
      const int mrow = (wave * 8 + mt) * 16 + ln;  // A[m=lane&15] [verified]
      const float* ap = x + (size_t)mrow * KD + kofs;
      const f32x4 a0 = *(const f32x4*)ap;
      const f32x4 a1 = *(const f32x4*)(ap + 4);
      uint4 af;
      af.x = pkbf(a0[0], a0[1]); af.y = pkbf(a0[2], a0[3]);
      af.z = pkbf(a1[0], a1[1]); af.w = pkbf(a1[2], a1[3]);
      acc[mt] = __builtin_amdgcn_mfma_f32_16x16x32_bf16(*(bf16x8*)&af,
                                                        *(bf16x8*)&bfr[k4],
                                                        acc[mt], 0, 0, 0);
    }
  }
  // C/D: row = quad*4+r (b within tile), col = ln (p)  [m89-verified]
  float* sp = s_part + (size_t)cz * SOP + (size_t)o * PD + ln;
#pragma unroll
  for (int mt = 0; mt < 8; ++mt) {
    const int mb0 = (wave * 8 + mt) * 16 + quad * 4;
#pragma unroll
    for (int r = 0; r < 4; ++r)
      sp[(size_t)(mb0 + r) * 160] = acc[mt][r];
  }
}

// ---- squash: reduce NCS partials + squash; emit vB (B-frag swizzle) or out.
__global__ __launch_bounds__(256) void squash_kernel(const float* __restrict__ s_part,
                                                     short* __restrict__ vB,
                                                     float* __restrict__ out,
                                                     int write_out) {
  const int t = blockIdx.x * 256 + threadIdx.x;  // < 81920, t = b*160 + n
  float sv = 0.f;
#pragma unroll 8
  for (int ch = 0; ch < NCS; ++ch) sv += s_part[(size_t)ch * SOP + t];
  float sq = sv * sv;
#pragma unroll
  for (int m = 1; m < 16; m <<= 1) sq += __shfl_xor(sq, m, 16);
  const float norm = sqrtf(sq + 1e-8f);
  const float val = sv * (sq / ((1.f + sq) * norm));
  if (write_out) {
    out[t] = val;
  } else {
    const int b = t / 160, n = t - b * 160;
    vB[((size_t)(b >> 5) * 160 + n) * 32 + (b & 31)] = f2bf(val);
  }
}

// ---- A: u_t[o][i] via MFMA (R13/R14/R15-verified), full K=512 in 4 chunks.
__global__ __launch_bounds__(256) void agg_kernel(const float* __restrict__ x,
                                                  const float* __restrict__ W,
                                                  const short* __restrict__ vB,
                                                  float* __restrict__ u_t) {
  __shared__ __align__(16) short Abuf[16 * 64 * 8];  // 16 KB
  const int tid = threadIdx.x;
  const int ig8 = blockIdx.x;
  const int mt = tid >> 6, lane = tid & 63;
  const int ln = lane & 15, quad = lane >> 4;
  f32x4 acc[10] = {};
  for (int kq = 0; kq < 4; ++kq) {
    const int b0 = kq * 128;
    __syncthreads();
#pragma unroll
    for (int j = 0; j < 8; ++j) {  // x -> A-frag layout [m120-verified]
      const int idx = tid + j * 256;
      const int b = idx >> 4, f4 = idx & 15;
      const float4 vx = *(const float4*)(x + (size_t)(b0 + b) * KD + ig8 * 64 + f4 * 4);
      const int kbl = b >> 5, qk = (b & 31) >> 3, jj = b & 7;
      const int mtt = f4 >> 2, mlb = (f4 & 3) * 4;
      short* dst = Abuf + (((mtt * 4 + kbl) * 64 + qk * 16 + mlb) * 8 + jj);
      dst[0] = f2bf(vx.x); dst[8] = f2bf(vx.y); dst[16] = f2bf(vx.z); dst[24] = f2bf(vx.w);
    }
    __syncthreads();
#pragma unroll
    for (int kbb = 0; kbb < 4; ++kbb) {
      const bf16x8 af = *(const bf16x8*)(Abuf + ((mt * 4 + kbb) * 64 + lane) * 8);
      const short* bp = vB + ((size_t)((kq * 4 + kbb) * 160) + ln) * 32 + quad * 8;
#pragma unroll
      for (int nt = 0; nt < 10; ++nt) {
        const bf16x8 bf = *(const bf16x8*)(bp + nt * 512);
        acc[nt] = __builtin_amdgcn_mfma_f32_16x16x32_bf16(af, bf, acc[nt], 0, 0, 0);
      }
    }
  }
  const int i = ig8 * 8 + mt * 2 + (quad >> 1);
  const int qb = (quad & 1) * 4;
#pragma unroll
  for (int nt = 0; nt < 10; ++nt) {
    const float4 wv = *(const float4*)(W + (((size_t)i * OD + nt) * PD + ln) * QD + qb);
    float pa = acc[nt][0] * wv.x + acc[nt][1] * wv.y + acc[nt][2] * wv.z + acc[nt][3] * wv.w;
    pa += __shfl_xor(pa, 1); pa += __shfl_xor(pa, 2); pa += __shfl_xor(pa, 4);
    pa += __shfl_xor(pa, 8); pa += __shfl_xor(pa, 16);
    if ((lane & 31) == 0) u_t[(size_t)nt * IC + i] = pa * (1.0f / (float)B);
  }
}

// ---- launch: 8 dispatches ---------------------------------------------------

extern "C" void kernel_launch(void* const* d_in, const int* in_sizes, int n_in,
                              void* d_out, int out_size, void* d_ws, size_t ws_size,
                              hipStream_t stream) {
  const float* x = (const float*)d_in[0];  // [512,1152,8] fp32
  const float* W = (const float*)d_in[1];  // [1152,10,16,8] fp32
  float* out = (float*)d_out;              // [512,10,16] fp32

  // workspace ~23.9 MB of ~268 MB; all buffers written before read each call
  float* ws = (float*)d_ws;
  float* s_part = ws;                        // 72*81920
  float* u_t = s_part + (size_t)NCS * SOP;   // 11520
  float* bijA = u_t + IO;                    // 11520
  short* vB = (short*)(bijA + IO);           // 16*160*32 bf16

  f_kernel<<<OD * NCS, 256, 0, stream>>>(x, W, u_t, bijA, s_part, 0);
  squash_kernel<<<SOP / 256, 256, 0, stream>>>(s_part, vB, out, 0);
  agg_kernel<<<144, 256, 0, stream>>>(x, W, vB, u_t);
  f_kernel<<<OD * NCS, 256, 0, stream>>>(x, W, u_t, bijA, s_part, 1);
  squash_kernel<<<SOP / 256, 256, 0, stream>>>(s_part, vB, out, 0);
  agg_kernel<<<144, 256, 0, stream>>>(x, W, vB, u_t);
  f_kernel<<<OD * NCS, 256, 0, stream>>>(x, W, u_t, bijA, s_part, 2);
  squash_kernel<<<SOP / 256, 256, 0, stream>>>(s_part, vB, out, 1);
}